// Round 3
// baseline (371.543 us; speedup 1.0000x reference)
//
#include <hip/hip_runtime.h>
#include <hip/hip_bf16.h>
#include <math.h>

typedef __bf16 bf16;
typedef __bf16 v8bf __attribute__((ext_vector_type(8)));
typedef __bf16 v4bf __attribute__((ext_vector_type(4)));
typedef __bf16 v2bf __attribute__((ext_vector_type(2)));
typedef float  v4f  __attribute__((ext_vector_type(4)));

#define FDIM 256
#define BKT_CAP 8192
#define AROW 264        // LDS A row stride (528B -> 2-way bank aliasing, free)
#define GEMM_BLOCKS 512

// ---------------- utility ----------------

__global__ __launch_bounds__(256) void flag_kernel(float* __restrict__ out, int n) {
  int i = blockIdx.x * 256 + threadIdx.x;
  if (i < n) out[i] = 1.0e9f;
}

// ---------------- K1: transposes + per-block bucket hists + V projection -------
__global__ __launch_bounds__(256) void k1_prep(const float* __restrict__ W1,
                                               const float* __restrict__ W2,
                                               bf16* __restrict__ Wt1,
                                               bf16* __restrict__ Wt2,
                                               const int* __restrict__ dst,
                                               int* __restrict__ phist,
                                               const float* __restrict__ Wl,
                                               const float* __restrict__ b2,
                                               const float* __restrict__ bl,
                                               float4* __restrict__ V,
                                               float* __restrict__ cc,
                                               int E, int N, int nbkt) {
  __shared__ int h[256];
  __shared__ float sWl[1024];   // Wl[512][2]
  __shared__ float red[256];
  int b = blockIdx.x;
  int t = threadIdx.x;
  if (b < 512) {
    const float* W = (b >> 8) ? W2 : W1;
    bf16* Wt = (b >> 8) ? Wt2 : Wt1;
    int k = b & 255;
    Wt[t * FDIM + k] = (bf16)W[k * FDIM + t];
  } else if (b < 768) {
    int pb = b - 512;  // 0..255
    h[t] = 0;
    __syncthreads();
    for (int e = pb * 256 + t; e < E; e += 256 * 256) {
      int d = dst[e];
      d = d < 0 ? 0 : (d >= N ? N - 1 : d);
      atomicAdd(&h[d >> 8], 1);
    }
    __syncthreads();
    phist[pb * 256 + t] = h[t];   // write ALL slots (p2 sums them; no memset)
  } else {
    // V[k] = (W2[k]·Wl_top0, W2[k]·Wl_top1, W2[k]·Wl_bot0, W2[k]·Wl_bot1)
#pragma unroll
    for (int j = 0; j < 4; ++j) sWl[j * 256 + t] = Wl[j * 256 + t];
    __syncthreads();
    const float* w2row = W2 + (size_t)t * FDIM;
    float4 acc = make_float4(0.f, 0.f, 0.f, 0.f);
    for (int j = 0; j < 256; ++j) {
      float w = w2row[j];
      acc.x += w * sWl[2 * j + 0];
      acc.y += w * sWl[2 * j + 1];
      acc.z += w * sWl[512 + 2 * j + 0];
      acc.w += w * sWl[512 + 2 * j + 1];
    }
    V[t] = acc;
    // cc[c] = sum_j b2[j]*(Wl[j][c] + Wl[256+j][c]) + bl[c]
    float bj = b2[t];
    red[t] = bj * (sWl[2 * t + 0] + sWl[512 + 2 * t + 0]);
    __syncthreads();
    if (t == 0) {
      float s = 0.f;
      for (int j = 0; j < 256; ++j) s += red[j];
      cc[0] = s + bl[0];
    }
    __syncthreads();
    red[t] = bj * (sWl[2 * t + 1] + sWl[512 + 2 * t + 1]);
    __syncthreads();
    if (t == 0) {
      float s = 0.f;
      for (int j = 0; j < 256; ++j) s += red[j];
      cc[1] = s + bl[1];
    }
  }
}

// ---------------- p2: sum per-block hists, scan -> bbase/gcur; offs[N]=E ------
__global__ __launch_bounds__(256) void p2_scan(const int* __restrict__ phist,
                                               int* __restrict__ bbase,
                                               int* __restrict__ gcur,
                                               int* __restrict__ offs,
                                               int nbkt, int Nn) {
  __shared__ int wsum[4];
  int t = threadIdx.x, lane = t & 63, wv = t >> 6;
  int v = 0;
  for (int pb = 0; pb < 256; ++pb) v += phist[pb * 256 + t];  // coalesced across t
  if (t >= nbkt) v = 0;
  int x = v;
#pragma unroll
  for (int d = 1; d < 64; d <<= 1) {
    int y = __shfl_up(x, d, 64);
    if (lane >= d) x += y;
  }
  if (lane == 63) wsum[wv] = x;
  __syncthreads();
  int woff = 0;
  if (wv >= 1) woff += wsum[0];
  if (wv >= 2) woff += wsum[1];
  if (wv >= 3) woff += wsum[2];
  int incl = woff + x;
  int excl = incl - v;
  if (t < nbkt) { bbase[t] = excl; gcur[t] = excl; }
  if (t == 255) {
    bbase[nbkt] = incl;
    offs[Nn] = incl;
  }
}

// ---------------- GEMM v4 body (used for gemm1 only now) ----------------

__device__ inline void stage64(const float* __restrict__ A, bf16* __restrict__ As,
                               int row0, int M, int tid) {
#pragma unroll
  for (int j = 0; j < 8; ++j) {
    int g = j * 2048 + tid * 8;
    int r = g >> 8, c = g & 255;
    int gr = row0 + r; if (gr >= M) gr = M - 1;
    const float* p = A + (size_t)gr * FDIM + c;
    float4 f0 = *reinterpret_cast<const float4*>(p);
    float4 f1 = *reinterpret_cast<const float4*>(p + 4);
    v8bf o;
    o[0] = (bf16)f0.x; o[1] = (bf16)f0.y; o[2] = (bf16)f0.z; o[3] = (bf16)f0.w;
    o[4] = (bf16)f1.x; o[5] = (bf16)f1.y; o[6] = (bf16)f1.z; o[7] = (bf16)f1.w;
    *reinterpret_cast<v8bf*>(As + r * AROW + c) = o;
  }
}

__device__ inline void gemm_body(const float* __restrict__ A, const bf16* __restrict__ Bt,
                                 bf16* __restrict__ C, int M, int bid, int nblocks,
                                 bf16* __restrict__ As) {
  const int K = FDIM, N = FDIM;
  int tid = threadIdx.x;
  int wave = tid >> 6;
  int lane = tid & 63;
  int l15 = lane & 15, quad = lane >> 4;

  v8bf bfr[4][8];
#pragma unroll
  for (int nn = 0; nn < 4; ++nn) {
    const bf16* bp = Bt + (size_t)(wave * 64 + nn * 16 + l15) * K + quad * 8;
#pragma unroll
    for (int kk = 0; kk < 8; ++kk)
      bfr[nn][kk] = *reinterpret_cast<const v8bf*>(bp + kk * 32);
  }

  int ntiles = (M + 63) >> 6;
  for (int tile = bid; tile < ntiles; tile += nblocks) {
    int row0 = tile * 64;
    __syncthreads();
    stage64(A, As, row0, M, tid);
    __syncthreads();

#pragma unroll
    for (int st = 0; st < 4; ++st) {
      v8bf afr[8];
#pragma unroll
      for (int kk = 0; kk < 8; ++kk)
        afr[kk] = *reinterpret_cast<const v8bf*>(As + (st * 16 + l15) * AROW + quad * 8 + kk * 32);

      v4f acc[4];
#pragma unroll
      for (int nn = 0; nn < 4; ++nn) acc[nn] = (v4f){0.f, 0.f, 0.f, 0.f};

#pragma unroll
      for (int kk = 0; kk < 8; ++kk)
#pragma unroll
        for (int nn = 0; nn < 4; ++nn)
          acc[nn] = __builtin_amdgcn_mfma_f32_16x16x32_bf16(afr[kk], bfr[nn][kk], acc[nn], 0, 0, 0);

#pragma unroll
      for (int nn = 0; nn < 4; ++nn)
#pragma unroll
        for (int r = 0; r < 4; ++r) {
          int row = row0 + st * 16 + quad * 4 + r;
          int col = wave * 64 + nn * 16 + l15;
          if (row < M) C[(size_t)row * N + col] = (bf16)acc[nn][r];
        }
    }
  }
}

// ---------------- p3 body: LDS-binned scatter into bucket regions ----------------
__device__ inline void p3_body(const int* __restrict__ src, const int* __restrict__ dst,
                               const float* __restrict__ ew, int* __restrict__ gcur,
                               uint2* __restrict__ tmp, int E, int N, int nbkt,
                               int pb, int nblocks, int* h, int* base, int* cnt) {
  int t = threadIdx.x;
  int chunk = (E + nblocks - 1) / nblocks;
  int lo = pb * chunk;
  int hi = lo + chunk; if (hi > E) hi = E;
  h[t] = 0; cnt[t] = 0;
  __syncthreads();
  for (int e = lo + t; e < hi; e += 256) {
    int d = dst[e];
    d = d < 0 ? 0 : (d >= N ? N - 1 : d);
    atomicAdd(&h[d >> 8], 1);
  }
  __syncthreads();
  if (t < nbkt) base[t] = atomicAdd(&gcur[t], h[t]);
  __syncthreads();
  for (int e = lo + t; e < hi; e += 256) {
    int d = dst[e];
    d = d < 0 ? 0 : (d >= N ? N - 1 : d);
    int b = d >> 8;
    int sv = src[e];
    sv = sv < 0 ? 0 : (sv >= N ? N - 1 : sv);
    unsigned int u = __float_as_uint(ew[e]);
    unsigned int wbits = ((u + 0x7FFFu + ((u >> 16) & 1u)) & 0xFFFF0000u);  // RN bf16
    unsigned int meta = wbits | (unsigned int)(sv & 0xFFFF);
    int r = atomicAdd(&cnt[b], 1);
    int pos = base[b] + r;
    if (pos >= 0 && pos < E) tmp[pos] = make_uint2(meta, (unsigned int)d);
  }
}

// ---------------- K3: gemm1 (0..511) + p3 (512..767) ----------------
__global__ __launch_bounds__(256, 2) void k3_gemm1_p3(const float* __restrict__ x,
                                                      const bf16* __restrict__ Wt1,
                                                      bf16* __restrict__ bufT, int M,
                                                      const int* __restrict__ src,
                                                      const int* __restrict__ dst,
                                                      const float* __restrict__ ew,
                                                      int* __restrict__ gcur,
                                                      uint2* __restrict__ tmp,
                                                      int E, int N, int nbkt) {
  __shared__ bf16 As[64 * AROW];
  __shared__ int h[256], base[256], cnt[256];
  if (blockIdx.x < GEMM_BLOCKS)
    gemm_body(x, Wt1, bufT, M, blockIdx.x, GEMM_BLOCKS, As);
  else
    p3_body(src, dst, ew, gcur, tmp, E, N, nbkt, blockIdx.x - GEMM_BLOCKS, 256, h, base, cnt);
}

// ---------------- p4: per-bucket LDS count-sort -> pmeta + node offsets --------
// Also zeroes G (agg1G accumulates into it with atomics).
__global__ __launch_bounds__(256) void p4_sort(const uint2* __restrict__ tmp,
                                               const int* __restrict__ bbase,
                                               unsigned int* __restrict__ pmeta,
                                               int* __restrict__ offs,
                                               float4* __restrict__ G,
                                               int Nn, int E) {
  __shared__ uint2 ent[BKT_CAP];
  __shared__ int h2[256], ex2[256], c2[256];
  __shared__ int wsum[4];
  int b = blockIdx.x, t = threadIdx.x, lane = t & 63, wv = t >> 6;
  int nodez = (b << 8) + t;
  if (nodez < Nn) G[nodez] = make_float4(0.f, 0.f, 0.f, 0.f);
  int s0 = bbase[b], s1 = bbase[b + 1];
  int count = s1 - s0;
  if (count < 0) count = 0;
  if (count > BKT_CAP) count = BKT_CAP;
  for (int i = t; i < count; i += 256) ent[i] = tmp[s0 + i];
  h2[t] = 0; c2[t] = 0;
  __syncthreads();
  for (int i = t; i < count; i += 256) atomicAdd(&h2[ent[i].y & 255u], 1);
  __syncthreads();
  int v = h2[t];
  int x = v;
#pragma unroll
  for (int d = 1; d < 64; d <<= 1) {
    int y = __shfl_up(x, d, 64);
    if (lane >= d) x += y;
  }
  if (lane == 63) wsum[wv] = x;
  __syncthreads();
  int woff = 0;
  if (wv >= 1) woff += wsum[0];
  if (wv >= 2) woff += wsum[1];
  if (wv >= 3) woff += wsum[2];
  int excl = woff + x - v;
  ex2[t] = excl;
  int node = (b << 8) + t;
  if (node < Nn) offs[node] = s0 + excl;
  __syncthreads();
  for (int i = t; i < count; i += 256) {
    int l = (int)(ent[i].y & 255u);
    int r = atomicAdd(&c2[l], 1);
    int pos = s0 + ex2[l] + r;
    if (pos >= 0 && pos < E) pmeta[pos] = ent[i].x;
  }
}

// ---------------- agg1G v4: feature-sliced (L2-resident) SpMM + layer-2 collapse ----
// slice = blockIdx & 7 -> with round-robin block->XCD dispatch, each XCD's L2 only
// sees a 50000 x 32 x 2B = 3.2 MB slice of T (fits 4 MiB) -> gathers become L2 hits.
// Wave = 1 node: 4 edge-groups x 16 feature-lanes x 2 feats (v2bf, 64B/line/edge).
// Partial projection per slice atomically accumulated into G (zeroed in p4).
__global__ __launch_bounds__(256) void agg1G(const bf16* __restrict__ T,
                                             const unsigned int* __restrict__ pmeta,
                                             const int* __restrict__ offsets,
                                             const float* __restrict__ bias,
                                             const float4* __restrict__ V,
                                             float4* __restrict__ G, int N, int E) {
  int slice = blockIdx.x & 7;
  int chunk = blockIdx.x >> 3;
  int nchunk = gridDim.x >> 3;
  int wv = threadIdx.x >> 6;
  int lane = threadIdx.x & 63;
  int grp = lane >> 4;            // 4 edge groups
  int l16 = lane & 15;            // 16 feature lanes
  int f = slice * 32 + l16 * 2;
  const bf16* Tf = T + f;

  // hoisted per-lane constants
  float bb0 = bias[f], bb1 = bias[f + 1];
  float4 v0 = V[f], v1 = V[f + 1];

  int wid = chunk * 4 + wv;
  int stride = nchunk * 4;
  for (int node = wid; node < N; node += stride) {
    int nb = __builtin_amdgcn_readfirstlane(node);
    int beg = offsets[nb], end = offsets[nb + 1];
    beg = beg < 0 ? 0 : (beg > E ? E : beg);
    end = end < beg ? beg : (end > E ? E : end);
    int cnt = end - beg;
    int g0 = (cnt * grp) >> 2;
    int g1 = (cnt * (grp + 1)) >> 2;
    const unsigned int* m = pmeta + beg;

    float a0 = 0.f, a1 = 0.f;
    int p = g0;
    for (; p + 4 <= g1; p += 4) {
      unsigned int m0 = __builtin_nontemporal_load(&m[p + 0]);
      unsigned int m1 = __builtin_nontemporal_load(&m[p + 1]);
      unsigned int m2 = __builtin_nontemporal_load(&m[p + 2]);
      unsigned int m3 = __builtin_nontemporal_load(&m[p + 3]);
      v2bf t0 = *reinterpret_cast<const v2bf*>(Tf + ((size_t)(m0 & 0xFFFFu) << 8));
      v2bf t1 = *reinterpret_cast<const v2bf*>(Tf + ((size_t)(m1 & 0xFFFFu) << 8));
      v2bf t2 = *reinterpret_cast<const v2bf*>(Tf + ((size_t)(m2 & 0xFFFFu) << 8));
      v2bf t3 = *reinterpret_cast<const v2bf*>(Tf + ((size_t)(m3 & 0xFFFFu) << 8));
      float w0 = __uint_as_float(m0 & 0xFFFF0000u);
      float w1 = __uint_as_float(m1 & 0xFFFF0000u);
      float w2 = __uint_as_float(m2 & 0xFFFF0000u);
      float w3 = __uint_as_float(m3 & 0xFFFF0000u);
      a0 += w0 * (float)t0[0]; a1 += w0 * (float)t0[1];
      a0 += w1 * (float)t1[0]; a1 += w1 * (float)t1[1];
      a0 += w2 * (float)t2[0]; a1 += w2 * (float)t2[1];
      a0 += w3 * (float)t3[0]; a1 += w3 * (float)t3[1];
    }
    for (; p < g1; ++p) {
      unsigned int mv = __builtin_nontemporal_load(&m[p]);
      float w = __uint_as_float(mv & 0xFFFF0000u);
      v2bf tv = *reinterpret_cast<const v2bf*>(Tf + ((size_t)(mv & 0xFFFFu) << 8));
      a0 += w * (float)tv[0];
      a1 += w * (float)tv[1];
    }

    // combine the 4 edge-groups (linear pre-relu sums): butterfly over lane bits 4,5
    a0 += __shfl_xor(a0, 16, 64); a0 += __shfl_xor(a0, 32, 64);
    a1 += __shfl_xor(a1, 16, 64); a1 += __shfl_xor(a1, 32, 64);

    float r0 = fmaxf(a0 + bb0, 0.f);
    float r1 = fmaxf(a1 + bb1, 0.f);

    float gx = r0 * v0.x + r1 * v1.x;
    float gy = r0 * v0.y + r1 * v1.y;
    float gz = r0 * v0.z + r1 * v1.z;
    float gw = r0 * v0.w + r1 * v1.w;
#pragma unroll
    for (int d = 1; d < 16; d <<= 1) {
      gx += __shfl_xor(gx, d, 64);
      gy += __shfl_xor(gy, d, 64);
      gz += __shfl_xor(gz, d, 64);
      gw += __shfl_xor(gw, d, 64);
    }
    if (lane == 0) {
      float* gp = reinterpret_cast<float*>(&G[node]);
      atomicAdd(gp + 0, gx);
      atomicAdd(gp + 1, gy);
      atomicAdd(gp + 2, gz);
      atomicAdd(gp + 3, gw);
    }
  }
}

// ---------------- aggP: P[n] = sum_e w_e * G[src_e]  (16B/edge, L2-resident table) ----
__global__ __launch_bounds__(256) void aggP(const float4* __restrict__ G,
                                            const unsigned int* __restrict__ pmeta,
                                            const int* __restrict__ offsets,
                                            float4* __restrict__ P, int N, int E) {
  int node = blockIdx.x * 256 + threadIdx.x;
  if (node >= N) return;
  int beg = offsets[node], end = offsets[node + 1];
  beg = beg < 0 ? 0 : (beg > E ? E : beg);
  end = end < beg ? beg : (end > E ? E : end);
  float ax = 0.f, ay = 0.f, az = 0.f, aw = 0.f;
  int p = beg;
  for (; p + 4 <= end; p += 4) {
    unsigned int m0 = pmeta[p + 0], m1 = pmeta[p + 1], m2 = pmeta[p + 2], m3 = pmeta[p + 3];
    int s0 = (int)(m0 & 0xFFFFu); s0 = s0 >= N ? N - 1 : s0;
    int s1 = (int)(m1 & 0xFFFFu); s1 = s1 >= N ? N - 1 : s1;
    int s2 = (int)(m2 & 0xFFFFu); s2 = s2 >= N ? N - 1 : s2;
    int s3 = (int)(m3 & 0xFFFFu); s3 = s3 >= N ? N - 1 : s3;
    float4 g0 = G[s0], g1 = G[s1], g2 = G[s2], g3 = G[s3];
    float w0 = __uint_as_float(m0 & 0xFFFF0000u);
    float w1 = __uint_as_float(m1 & 0xFFFF0000u);
    float w2 = __uint_as_float(m2 & 0xFFFF0000u);
    float w3 = __uint_as_float(m3 & 0xFFFF0000u);
    ax += w0 * g0.x + w1 * g1.x + w2 * g2.x + w3 * g3.x;
    ay += w0 * g0.y + w1 * g1.y + w2 * g2.y + w3 * g3.y;
    az += w0 * g0.z + w1 * g1.z + w2 * g2.z + w3 * g3.z;
    aw += w0 * g0.w + w1 * g1.w + w2 * g2.w + w3 * g3.w;
  }
  for (; p < end; ++p) {
    unsigned int mm = pmeta[p];
    int s = (int)(mm & 0xFFFFu); s = s >= N ? N - 1 : s;
    float w = __uint_as_float(mm & 0xFFFF0000u);
    float4 g = G[s];
    ax += w * g.x; ay += w * g.y; az += w * g.z; aw += w * g.w;
  }
  P[node] = make_float4(ax, ay, az, aw);
}

// ---------------- query: logits from P + cc, log-softmax ----------------
__global__ __launch_bounds__(256) void query_small(const int* __restrict__ qe,
                                                   const float4* __restrict__ P,
                                                   const float* __restrict__ cc,
                                                   float* __restrict__ out, int Q, int N) {
  int q = blockIdx.x * 256 + threadIdx.x;
  if (q >= Q) return;
  int n0 = qe[2 * q + 0]; n0 = n0 < 0 ? 0 : (n0 >= N ? N - 1 : n0);
  int n1 = qe[2 * q + 1]; n1 = n1 < 0 ? 0 : (n1 >= N ? N - 1 : n1);
  float4 p0 = P[n0];
  float4 p1 = P[n1];
  float l0 = p0.x + p1.z + cc[0];
  float l1 = p0.y + p1.w + cc[1];
  float m = fmaxf(l0, l1);
  float lse = m + logf(expf(l0 - m) + expf(l1 - m));
  out[2 * q + 0] = l0 - lse;
  out[2 * q + 1] = l1 - lse;
}

// ---------------- host launcher ----------------

extern "C" void kernel_launch(void* const* d_in, const int* in_sizes, int n_in,
                              void* d_out, int out_size, void* d_ws, size_t ws_size,
                              hipStream_t stream) {
  const float* x  = (const float*)d_in[0];
  const int*   ei = (const int*)d_in[1];
  const int*   qe = (const int*)d_in[2];
  const float* ew = (const float*)d_in[3];
  const float* W1 = (const float*)d_in[4];
  const float* b1 = (const float*)d_in[5];
  const float* W2 = (const float*)d_in[6];
  const float* b2 = (const float*)d_in[7];
  const float* Wl = (const float*)d_in[8];
  const float* bl = (const float*)d_in[9];

  int N = in_sizes[0] / FDIM;  // 50000
  int E = in_sizes[1] / 2;     // 1,000,000
  int Q = in_sizes[2] / 2;     // 100,000
  const int* srcv = ei;
  const int* dstv = ei + E;
  int nbkt = (N + 255) >> 8;   // 196

  size_t off = 0;
  auto alloc = [&](size_t bytes) -> void* {
    void* p = (char*)d_ws + off;
    off += (bytes + 255) & ~(size_t)255;
    return p;
  };
  bf16* bufT  = (bf16*)alloc((size_t)N * FDIM * 2);   // t1 = x@W1
  uint2* tmp  = (uint2*)alloc((size_t)E * 8);         // bucket-scattered {meta,dst}
  bf16* Wt1   = (bf16*)alloc((size_t)FDIM * FDIM * 2);
  bf16* Wt2   = (bf16*)alloc((size_t)FDIM * FDIM * 2);  // (unused by math now; kept tiny)
  int* offs   = (int*)alloc((size_t)(N + 1) * 4);
  unsigned int* pmeta = (unsigned int*)alloc((size_t)E * 4);
  float4* G   = (float4*)alloc((size_t)N * 16);
  float4* P   = (float4*)alloc((size_t)N * 16);
  float4* V   = (float4*)alloc(256 * 16);
  float* cc   = (float*)alloc(2 * 4);
  int* phist  = (int*)alloc(256 * 256 * 4);
  int* bbase  = (int*)alloc(257 * 4);
  int* gcur   = (int*)alloc(256 * 4);

  if (off > ws_size) {
    flag_kernel<<<(out_size + 255) / 256, 256, 0, stream>>>((float*)d_out, out_size);
    return;
  }

  // K1: transposes + per-block hists (no memset, no global atomics) + V/cc
  k1_prep<<<769, 256, 0, stream>>>(W1, W2, Wt1, Wt2, dstv, phist, Wl, b2, bl, V, cc,
                                   E, N, nbkt);
  p2_scan<<<1, 256, 0, stream>>>(phist, bbase, gcur, offs, nbkt, N);
  // K3: gemm1 (t1 = x@W1) overlapped with p3 edge scatter
  k3_gemm1_p3<<<GEMM_BLOCKS + 256, 256, 0, stream>>>(x, Wt1, bufT, N,
                                                     srcv, dstv, ew, gcur, tmp, E, N, nbkt);
  // p4: sort buckets + zero G
  p4_sort<<<nbkt, 256, 0, stream>>>(tmp, bbase, pmeta, offs, G, N, E);

  // layer 1 + in-register layer-2 collapse, feature-sliced for L2 residency:
  // 2048 blocks = 8 slices x 256 chunks x 4 waves; slice = blockIdx & 7 (XCD-aligned)
  agg1G<<<2048, 256, 0, stream>>>(bufT, pmeta, offs, b1, V, G, N, E);

  // layer 2 aggregation in 4-dim space: P[n] = sum_e w_e G[src_e]
  aggP<<<(N + 255) / 256, 256, 0, stream>>>(G, pmeta, offs, P, N, E);

  // per-query combine + log-softmax (cc folds b2/bl constants)
  query_small<<<(Q + 255) / 256, 256, 0, stream>>>(qe, P, cc, (float*)d_out, Q, N);
}

// Round 4
// 249.260 us; speedup vs baseline: 1.4906x; 1.4906x over previous
//
#include <hip/hip_runtime.h>
#include <hip/hip_bf16.h>
#include <math.h>

typedef __bf16 bf16;
typedef __bf16 v8bf __attribute__((ext_vector_type(8)));
typedef __bf16 v4bf __attribute__((ext_vector_type(4)));
typedef float  v4f  __attribute__((ext_vector_type(4)));

#define FDIM 256
#define BKT_CAP 8192
#define AROW 264        // LDS A row stride (528B -> 2-way bank aliasing, free)
#define GEMM_BLOCKS 352 // + 160 p3 blocks = 512 total -> all co-resident at 2 blk/CU
#define K3_BLOCKS 512
#define P3_BLOCKS (K3_BLOCKS - GEMM_BLOCKS)

// ---------------- utility ----------------

__global__ __launch_bounds__(256) void flag_kernel(float* __restrict__ out, int n) {
  int i = blockIdx.x * 256 + threadIdx.x;
  if (i < n) out[i] = 1.0e9f;
}

// ---------------- K1: Wt1 transpose + per-block bucket hists + V projection -------
// blocks 0..255: Wt1 transpose (Wt2 dropped — collapsed math never reads it);
// 256..511: per-block hist -> phist; block 512: V = W2 @ [Wl_top | Wl_bot] + cc[2].
__global__ __launch_bounds__(256) void k1_prep(const float* __restrict__ W1,
                                               const float* __restrict__ W2,
                                               bf16* __restrict__ Wt1,
                                               const int* __restrict__ dst,
                                               int* __restrict__ phist,
                                               const float* __restrict__ Wl,
                                               const float* __restrict__ b2,
                                               const float* __restrict__ bl,
                                               float4* __restrict__ V,
                                               float* __restrict__ cc,
                                               int E, int N, int nbkt) {
  __shared__ int h[256];
  __shared__ float sWl[1024];   // Wl[512][2]
  __shared__ float red[256];
  int b = blockIdx.x;
  int t = threadIdx.x;
  if (b < 256) {
    int k = b;
    Wt1[t * FDIM + k] = (bf16)W1[k * FDIM + t];
  } else if (b < 512) {
    int pb = b - 256;  // 0..255
    h[t] = 0;
    __syncthreads();
    for (int e = pb * 256 + t; e < E; e += 256 * 256) {
      int d = dst[e];
      d = d < 0 ? 0 : (d >= N ? N - 1 : d);
      atomicAdd(&h[d >> 8], 1);
    }
    __syncthreads();
    phist[pb * 256 + t] = h[t];   // write ALL slots (p2 sums them; no memset)
  } else {
    // V[k] = (W2[k]·Wl_top0, W2[k]·Wl_top1, W2[k]·Wl_bot0, W2[k]·Wl_bot1)
#pragma unroll
    for (int j = 0; j < 4; ++j) sWl[j * 256 + t] = Wl[j * 256 + t];
    __syncthreads();
    const float* w2row = W2 + (size_t)t * FDIM;
    float4 acc = make_float4(0.f, 0.f, 0.f, 0.f);
    for (int j = 0; j < 256; ++j) {
      float w = w2row[j];
      acc.x += w * sWl[2 * j + 0];
      acc.y += w * sWl[2 * j + 1];
      acc.z += w * sWl[512 + 2 * j + 0];
      acc.w += w * sWl[512 + 2 * j + 1];
    }
    V[t] = acc;
    // cc[c] = sum_j b2[j]*(Wl[j][c] + Wl[256+j][c]) + bl[c]
    float bj = b2[t];
    red[t] = bj * (sWl[2 * t + 0] + sWl[512 + 2 * t + 0]);
    __syncthreads();
    if (t == 0) {
      float s = 0.f;
      for (int j = 0; j < 256; ++j) s += red[j];
      cc[0] = s + bl[0];
    }
    __syncthreads();
    red[t] = bj * (sWl[2 * t + 1] + sWl[512 + 2 * t + 1]);
    __syncthreads();
    if (t == 0) {
      float s = 0.f;
      for (int j = 0; j < 256; ++j) s += red[j];
      cc[1] = s + bl[1];
    }
  }
}

// ---------------- p2: sum per-block hists, scan -> bbase/gcur; offs[N]=E ------
__global__ __launch_bounds__(256) void p2_scan(const int* __restrict__ phist,
                                               int* __restrict__ bbase,
                                               int* __restrict__ gcur,
                                               int* __restrict__ offs,
                                               int nbkt, int Nn) {
  __shared__ int wsum[4];
  int t = threadIdx.x, lane = t & 63, wv = t >> 6;
  int v = 0;
  for (int pb = 0; pb < 256; ++pb) v += phist[pb * 256 + t];  // coalesced across t
  if (t >= nbkt) v = 0;
  int x = v;
#pragma unroll
  for (int d = 1; d < 64; d <<= 1) {
    int y = __shfl_up(x, d, 64);
    if (lane >= d) x += y;
  }
  if (lane == 63) wsum[wv] = x;
  __syncthreads();
  int woff = 0;
  if (wv >= 1) woff += wsum[0];
  if (wv >= 2) woff += wsum[1];
  if (wv >= 3) woff += wsum[2];
  int incl = woff + x;
  int excl = incl - v;
  if (t < nbkt) { bbase[t] = excl; gcur[t] = excl; }
  if (t == 255) {
    bbase[nbkt] = incl;
    offs[Nn] = incl;
  }
}

// ---------------- GEMM v4 body (used for gemm1 only now) ----------------

__device__ inline void stage64(const float* __restrict__ A, bf16* __restrict__ As,
                               int row0, int M, int tid) {
#pragma unroll
  for (int j = 0; j < 8; ++j) {
    int g = j * 2048 + tid * 8;
    int r = g >> 8, c = g & 255;
    int gr = row0 + r; if (gr >= M) gr = M - 1;
    const float* p = A + (size_t)gr * FDIM + c;
    float4 f0 = *reinterpret_cast<const float4*>(p);
    float4 f1 = *reinterpret_cast<const float4*>(p + 4);
    v8bf o;
    o[0] = (bf16)f0.x; o[1] = (bf16)f0.y; o[2] = (bf16)f0.z; o[3] = (bf16)f0.w;
    o[4] = (bf16)f1.x; o[5] = (bf16)f1.y; o[6] = (bf16)f1.z; o[7] = (bf16)f1.w;
    *reinterpret_cast<v8bf*>(As + r * AROW + c) = o;
  }
}

__device__ inline void gemm_body(const float* __restrict__ A, const bf16* __restrict__ Bt,
                                 bf16* __restrict__ C, int M, int bid, int nblocks,
                                 bf16* __restrict__ As) {
  const int K = FDIM, N = FDIM;
  int tid = threadIdx.x;
  int wave = tid >> 6;
  int lane = tid & 63;
  int l15 = lane & 15, quad = lane >> 4;

  v8bf bfr[4][8];
#pragma unroll
  for (int nn = 0; nn < 4; ++nn) {
    const bf16* bp = Bt + (size_t)(wave * 64 + nn * 16 + l15) * K + quad * 8;
#pragma unroll
    for (int kk = 0; kk < 8; ++kk)
      bfr[nn][kk] = *reinterpret_cast<const v8bf*>(bp + kk * 32);
  }

  int ntiles = (M + 63) >> 6;
  for (int tile = bid; tile < ntiles; tile += nblocks) {
    int row0 = tile * 64;
    __syncthreads();
    stage64(A, As, row0, M, tid);
    __syncthreads();

#pragma unroll
    for (int st = 0; st < 4; ++st) {
      v8bf afr[8];
#pragma unroll
      for (int kk = 0; kk < 8; ++kk)
        afr[kk] = *reinterpret_cast<const v8bf*>(As + (st * 16 + l15) * AROW + quad * 8 + kk * 32);

      v4f acc[4];
#pragma unroll
      for (int nn = 0; nn < 4; ++nn) acc[nn] = (v4f){0.f, 0.f, 0.f, 0.f};

#pragma unroll
      for (int kk = 0; kk < 8; ++kk)
#pragma unroll
        for (int nn = 0; nn < 4; ++nn)
          acc[nn] = __builtin_amdgcn_mfma_f32_16x16x32_bf16(afr[kk], bfr[nn][kk], acc[nn], 0, 0, 0);

#pragma unroll
      for (int nn = 0; nn < 4; ++nn)
#pragma unroll
        for (int r = 0; r < 4; ++r) {
          int row = row0 + st * 16 + quad * 4 + r;
          int col = wave * 64 + nn * 16 + l15;
          if (row < M) C[(size_t)row * N + col] = (bf16)acc[nn][r];
        }
    }
  }
}

// ---------------- p3 body: LDS-binned scatter into bucket regions ----------------
__device__ inline void p3_body(const int* __restrict__ src, const int* __restrict__ dst,
                               const float* __restrict__ ew, int* __restrict__ gcur,
                               uint2* __restrict__ tmp, int E, int N, int nbkt,
                               int pb, int nblocks, int* h, int* base, int* cnt) {
  int t = threadIdx.x;
  int chunk = (E + nblocks - 1) / nblocks;
  int lo = pb * chunk;
  int hi = lo + chunk; if (hi > E) hi = E;
  h[t] = 0; cnt[t] = 0;
  __syncthreads();
  for (int e = lo + t; e < hi; e += 256) {
    int d = dst[e];
    d = d < 0 ? 0 : (d >= N ? N - 1 : d);
    atomicAdd(&h[d >> 8], 1);
  }
  __syncthreads();
  if (t < nbkt) base[t] = atomicAdd(&gcur[t], h[t]);
  __syncthreads();
  for (int e = lo + t; e < hi; e += 256) {
    int d = dst[e];
    d = d < 0 ? 0 : (d >= N ? N - 1 : d);
    int b = d >> 8;
    int sv = src[e];
    sv = sv < 0 ? 0 : (sv >= N ? N - 1 : sv);
    unsigned int u = __float_as_uint(ew[e]);
    unsigned int wbits = ((u + 0x7FFFu + ((u >> 16) & 1u)) & 0xFFFF0000u);  // RN bf16
    unsigned int meta = wbits | (unsigned int)(sv & 0xFFFF);
    int r = atomicAdd(&cnt[b], 1);
    int pos = base[b] + r;
    if (pos >= 0 && pos < E) tmp[pos] = make_uint2(meta, (unsigned int)d);
  }
}

// ---------------- K3: gemm1 (0..GEMM_BLOCKS-1) + p3 (rest) — all co-resident ----
__global__ __launch_bounds__(256, 2) void k3_gemm1_p3(const float* __restrict__ x,
                                                      const bf16* __restrict__ Wt1,
                                                      bf16* __restrict__ bufT, int M,
                                                      const int* __restrict__ src,
                                                      const int* __restrict__ dst,
                                                      const float* __restrict__ ew,
                                                      int* __restrict__ gcur,
                                                      uint2* __restrict__ tmp,
                                                      int E, int N, int nbkt) {
  __shared__ bf16 As[64 * AROW];
  __shared__ int h[256], base[256], cnt[256];
  if (blockIdx.x < GEMM_BLOCKS)
    gemm_body(x, Wt1, bufT, M, blockIdx.x, GEMM_BLOCKS, As);
  else
    p3_body(src, dst, ew, gcur, tmp, E, N, nbkt, blockIdx.x - GEMM_BLOCKS, P3_BLOCKS,
            h, base, cnt);
}

// ---------------- p4: per-bucket LDS count-sort -> pmeta + node offsets --------
__global__ __launch_bounds__(256) void p4_sort(const uint2* __restrict__ tmp,
                                               const int* __restrict__ bbase,
                                               unsigned int* __restrict__ pmeta,
                                               int* __restrict__ offs,
                                               int Nn, int E) {
  __shared__ uint2 ent[BKT_CAP];
  __shared__ int h2[256], ex2[256], c2[256];
  __shared__ int wsum[4];
  int b = blockIdx.x, t = threadIdx.x, lane = t & 63, wv = t >> 6;
  int s0 = bbase[b], s1 = bbase[b + 1];
  int count = s1 - s0;
  if (count < 0) count = 0;
  if (count > BKT_CAP) count = BKT_CAP;
  for (int i = t; i < count; i += 256) ent[i] = tmp[s0 + i];
  h2[t] = 0; c2[t] = 0;
  __syncthreads();
  for (int i = t; i < count; i += 256) atomicAdd(&h2[ent[i].y & 255u], 1);
  __syncthreads();
  int v = h2[t];
  int x = v;
#pragma unroll
  for (int d = 1; d < 64; d <<= 1) {
    int y = __shfl_up(x, d, 64);
    if (lane >= d) x += y;
  }
  if (lane == 63) wsum[wv] = x;
  __syncthreads();
  int woff = 0;
  if (wv >= 1) woff += wsum[0];
  if (wv >= 2) woff += wsum[1];
  if (wv >= 3) woff += wsum[2];
  int excl = woff + x - v;
  ex2[t] = excl;
  int node = (b << 8) + t;
  if (node < Nn) offs[node] = s0 + excl;
  __syncthreads();
  for (int i = t; i < count; i += 256) {
    int l = (int)(ent[i].y & 255u);
    int r = atomicAdd(&c2[l], 1);
    int pos = s0 + ex2[l] + r;
    if (pos >= 0 && pos < E) pmeta[pos] = ent[i].x;
  }
}

// ---------------- agg1G (round-2 proven): grid-stride + scalarized meta ----
// Wave = 1 node at a time, grid-stride over nodes (~6 nodes/wave at 2048 blocks).
// bias/V fragments hoisted into registers once per wave. node is readfirstlane'd so
// offsets[] and pmeta[] loads scalarize (s_load), weights become SGPR broadcasts and
// row gathers become saddr-form loads with zero per-edge VALU address math.
__global__ __launch_bounds__(256) void agg1G(const bf16* __restrict__ T,
                                             const unsigned int* __restrict__ pmeta,
                                             const int* __restrict__ offsets,
                                             const float* __restrict__ bias,
                                             const float4* __restrict__ V,
                                             float4* __restrict__ G, int N, int E) {
  int wid = blockIdx.x * 4 + (threadIdx.x >> 6);
  int nw = gridDim.x * 4;
  int lane = threadIdx.x & 63;
  int f = lane * 4;
  const bf16* Tf = T + f;

  // hoisted per-lane constants (identical across the wave's nodes)
  float4 bb = *reinterpret_cast<const float4*>(bias + f);
  float4 v0 = V[f + 0], v1 = V[f + 1], v2 = V[f + 2], v3 = V[f + 3];

  for (int node = wid; node < N; node += nw) {
    int nb = __builtin_amdgcn_readfirstlane(node);
    int beg = offsets[nb], end = offsets[nb + 1];
    beg = beg < 0 ? 0 : (beg > E ? E : beg);
    end = end < beg ? beg : (end > E ? E : end);
    int cnt = end - beg;
    const unsigned int* m = pmeta + beg;

    float a0 = 0.f, a1 = 0.f, a2 = 0.f, a3 = 0.f;
    int p = 0;
    for (; p + 8 <= cnt; p += 8) {
      unsigned int mv0 = m[p + 0], mv1 = m[p + 1], mv2 = m[p + 2], mv3 = m[p + 3];
      unsigned int mv4 = m[p + 4], mv5 = m[p + 5], mv6 = m[p + 6], mv7 = m[p + 7];
      v4bf t0 = *reinterpret_cast<const v4bf*>(Tf + ((size_t)(mv0 & 0xFFFFu) << 8));
      v4bf t1 = *reinterpret_cast<const v4bf*>(Tf + ((size_t)(mv1 & 0xFFFFu) << 8));
      v4bf t2 = *reinterpret_cast<const v4bf*>(Tf + ((size_t)(mv2 & 0xFFFFu) << 8));
      v4bf t3 = *reinterpret_cast<const v4bf*>(Tf + ((size_t)(mv3 & 0xFFFFu) << 8));
      v4bf t4 = *reinterpret_cast<const v4bf*>(Tf + ((size_t)(mv4 & 0xFFFFu) << 8));
      v4bf t5 = *reinterpret_cast<const v4bf*>(Tf + ((size_t)(mv5 & 0xFFFFu) << 8));
      v4bf t6 = *reinterpret_cast<const v4bf*>(Tf + ((size_t)(mv6 & 0xFFFFu) << 8));
      v4bf t7 = *reinterpret_cast<const v4bf*>(Tf + ((size_t)(mv7 & 0xFFFFu) << 8));
      float w0 = __uint_as_float(mv0 & 0xFFFF0000u);
      float w1 = __uint_as_float(mv1 & 0xFFFF0000u);
      float w2 = __uint_as_float(mv2 & 0xFFFF0000u);
      float w3 = __uint_as_float(mv3 & 0xFFFF0000u);
      float w4 = __uint_as_float(mv4 & 0xFFFF0000u);
      float w5 = __uint_as_float(mv5 & 0xFFFF0000u);
      float w6 = __uint_as_float(mv6 & 0xFFFF0000u);
      float w7 = __uint_as_float(mv7 & 0xFFFF0000u);
      a0 += w0 * (float)t0[0]; a1 += w0 * (float)t0[1]; a2 += w0 * (float)t0[2]; a3 += w0 * (float)t0[3];
      a0 += w1 * (float)t1[0]; a1 += w1 * (float)t1[1]; a2 += w1 * (float)t1[2]; a3 += w1 * (float)t1[3];
      a0 += w2 * (float)t2[0]; a1 += w2 * (float)t2[1]; a2 += w2 * (float)t2[2]; a3 += w2 * (float)t2[3];
      a0 += w3 * (float)t3[0]; a1 += w3 * (float)t3[1]; a2 += w3 * (float)t3[2]; a3 += w3 * (float)t3[3];
      a0 += w4 * (float)t4[0]; a1 += w4 * (float)t4[1]; a2 += w4 * (float)t4[2]; a3 += w4 * (float)t4[3];
      a0 += w5 * (float)t5[0]; a1 += w5 * (float)t5[1]; a2 += w5 * (float)t5[2]; a3 += w5 * (float)t5[3];
      a0 += w6 * (float)t6[0]; a1 += w6 * (float)t6[1]; a2 += w6 * (float)t6[2]; a3 += w6 * (float)t6[3];
      a0 += w7 * (float)t7[0]; a1 += w7 * (float)t7[1]; a2 += w7 * (float)t7[2]; a3 += w7 * (float)t7[3];
    }
    for (; p < cnt; ++p) {
      unsigned int mv = m[p];
      float w = __uint_as_float(mv & 0xFFFF0000u);
      v4bf tv = *reinterpret_cast<const v4bf*>(Tf + ((size_t)(mv & 0xFFFFu) << 8));
      a0 += w * (float)tv[0];
      a1 += w * (float)tv[1];
      a2 += w * (float)tv[2];
      a3 += w * (float)tv[3];
    }

    float r0 = fmaxf(a0 + bb.x, 0.f);
    float r1 = fmaxf(a1 + bb.y, 0.f);
    float r2 = fmaxf(a2 + bb.z, 0.f);
    float r3 = fmaxf(a3 + bb.w, 0.f);

    float gx = r0 * v0.x + r1 * v1.x + r2 * v2.x + r3 * v3.x;
    float gy = r0 * v0.y + r1 * v1.y + r2 * v2.y + r3 * v3.y;
    float gz = r0 * v0.z + r1 * v1.z + r2 * v2.z + r3 * v3.z;
    float gw = r0 * v0.w + r1 * v1.w + r2 * v2.w + r3 * v3.w;
#pragma unroll
    for (int d = 32; d > 0; d >>= 1) {
      gx += __shfl_down(gx, d, 64);
      gy += __shfl_down(gy, d, 64);
      gz += __shfl_down(gz, d, 64);
      gw += __shfl_down(gw, d, 64);
    }
    if (lane == 0) G[node] = make_float4(gx, gy, gz, gw);
  }
}

// ---------------- aggP: P[n] = sum_e w_e * G[src_e]  (16B/edge, L2-resident table) ----
__global__ __launch_bounds__(256) void aggP(const float4* __restrict__ G,
                                            const unsigned int* __restrict__ pmeta,
                                            const int* __restrict__ offsets,
                                            float4* __restrict__ P, int N, int E) {
  int node = blockIdx.x * 256 + threadIdx.x;
  if (node >= N) return;
  int beg = offsets[node], end = offsets[node + 1];
  beg = beg < 0 ? 0 : (beg > E ? E : beg);
  end = end < beg ? beg : (end > E ? E : end);
  float ax = 0.f, ay = 0.f, az = 0.f, aw = 0.f;
  int p = beg;
  for (; p + 4 <= end; p += 4) {
    unsigned int m0 = pmeta[p + 0], m1 = pmeta[p + 1], m2 = pmeta[p + 2], m3 = pmeta[p + 3];
    int s0 = (int)(m0 & 0xFFFFu); s0 = s0 >= N ? N - 1 : s0;
    int s1 = (int)(m1 & 0xFFFFu); s1 = s1 >= N ? N - 1 : s1;
    int s2 = (int)(m2 & 0xFFFFu); s2 = s2 >= N ? N - 1 : s2;
    int s3 = (int)(m3 & 0xFFFFu); s3 = s3 >= N ? N - 1 : s3;
    float4 g0 = G[s0], g1 = G[s1], g2 = G[s2], g3 = G[s3];
    float w0 = __uint_as_float(m0 & 0xFFFF0000u);
    float w1 = __uint_as_float(m1 & 0xFFFF0000u);
    float w2 = __uint_as_float(m2 & 0xFFFF0000u);
    float w3 = __uint_as_float(m3 & 0xFFFF0000u);
    ax += w0 * g0.x + w1 * g1.x + w2 * g2.x + w3 * g3.x;
    ay += w0 * g0.y + w1 * g1.y + w2 * g2.y + w3 * g3.y;
    az += w0 * g0.z + w1 * g1.z + w2 * g2.z + w3 * g3.z;
    aw += w0 * g0.w + w1 * g1.w + w2 * g2.w + w3 * g3.w;
  }
  for (; p < end; ++p) {
    unsigned int mm = pmeta[p];
    int s = (int)(mm & 0xFFFFu); s = s >= N ? N - 1 : s;
    float w = __uint_as_float(mm & 0xFFFF0000u);
    float4 g = G[s];
    ax += w * g.x; ay += w * g.y; az += w * g.z; aw += w * g.w;
  }
  P[node] = make_float4(ax, ay, az, aw);
}

// ---------------- query: logits from P + cc, log-softmax ----------------
__global__ __launch_bounds__(256) void query_small(const int* __restrict__ qe,
                                                   const float4* __restrict__ P,
                                                   const float* __restrict__ cc,
                                                   float* __restrict__ out, int Q, int N) {
  int q = blockIdx.x * 256 + threadIdx.x;
  if (q >= Q) return;
  int n0 = qe[2 * q + 0]; n0 = n0 < 0 ? 0 : (n0 >= N ? N - 1 : n0);
  int n1 = qe[2 * q + 1]; n1 = n1 < 0 ? 0 : (n1 >= N ? N - 1 : n1);
  float4 p0 = P[n0];
  float4 p1 = P[n1];
  float l0 = p0.x + p1.z + cc[0];
  float l1 = p0.y + p1.w + cc[1];
  float m = fmaxf(l0, l1);
  float lse = m + logf(expf(l0 - m) + expf(l1 - m));
  out[2 * q + 0] = l0 - lse;
  out[2 * q + 1] = l1 - lse;
}

// ---------------- host launcher ----------------

extern "C" void kernel_launch(void* const* d_in, const int* in_sizes, int n_in,
                              void* d_out, int out_size, void* d_ws, size_t ws_size,
                              hipStream_t stream) {
  const float* x  = (const float*)d_in[0];
  const int*   ei = (const int*)d_in[1];
  const int*   qe = (const int*)d_in[2];
  const float* ew = (const float*)d_in[3];
  const float* W1 = (const float*)d_in[4];
  const float* b1 = (const float*)d_in[5];
  const float* W2 = (const float*)d_in[6];
  const float* b2 = (const float*)d_in[7];
  const float* Wl = (const float*)d_in[8];
  const float* bl = (const float*)d_in[9];

  int N = in_sizes[0] / FDIM;  // 50000
  int E = in_sizes[1] / 2;     // 1,000,000
  int Q = in_sizes[2] / 2;     // 100,000
  const int* srcv = ei;
  const int* dstv = ei + E;
  int nbkt = (N + 255) >> 8;   // 196

  size_t off = 0;
  auto alloc = [&](size_t bytes) -> void* {
    void* p = (char*)d_ws + off;
    off += (bytes + 255) & ~(size_t)255;
    return p;
  };
  bf16* bufT  = (bf16*)alloc((size_t)N * FDIM * 2);   // t1 = x@W1
  uint2* tmp  = (uint2*)alloc((size_t)E * 8);         // bucket-scattered {meta,dst}
  bf16* Wt1   = (bf16*)alloc((size_t)FDIM * FDIM * 2);
  int* offs   = (int*)alloc((size_t)(N + 1) * 4);
  unsigned int* pmeta = (unsigned int*)alloc((size_t)E * 4);
  float4* G   = (float4*)alloc((size_t)N * 16);
  float4* P   = (float4*)alloc((size_t)N * 16);
  float4* V   = (float4*)alloc(256 * 16);
  float* cc   = (float*)alloc(2 * 4);
  int* phist  = (int*)alloc(256 * 256 * 4);
  int* bbase  = (int*)alloc(257 * 4);
  int* gcur   = (int*)alloc(256 * 4);

  if (off > ws_size) {
    flag_kernel<<<(out_size + 255) / 256, 256, 0, stream>>>((float*)d_out, out_size);
    return;
  }

  // K1: Wt1 transpose + per-block hists + V/cc  (513 blocks; Wt2 dropped)
  k1_prep<<<513, 256, 0, stream>>>(W1, W2, Wt1, dstv, phist, Wl, b2, bl, V, cc,
                                   E, N, nbkt);
  p2_scan<<<1, 256, 0, stream>>>(phist, bbase, gcur, offs, nbkt, N);
  // K3: gemm1 (t1 = x@W1) truly overlapped with p3 edge scatter (512 blocks, all resident)
  k3_gemm1_p3<<<K3_BLOCKS, 256, 0, stream>>>(x, Wt1, bufT, N,
                                             srcv, dstv, ew, gcur, tmp, E, N, nbkt);
  p4_sort<<<nbkt, 256, 0, stream>>>(tmp, bbase, pmeta, offs, N, E);

  // layer 1 + in-register layer-2 collapse: G[n] = relu(agg(t1)+b1) @ V
  agg1G<<<2048, 256, 0, stream>>>(bufT, pmeta, offs, b1, V, G, N, E);

  // layer 2 aggregation in 4-dim space: P[n] = sum_e w_e G[src_e]
  aggP<<<(N + 255) / 256, 256, 0, stream>>>(G, pmeta, offs, P, N, E);

  // per-query combine + log-softmax (cc folds b2/bl constants)
  query_small<<<(Q + 255) / 256, 256, 0, stream>>>(qe, P, cc, (float*)d_out, Q, N);
}